// Round 1
// baseline (1756.472 us; speedup 1.0000x reference)
//
#include <hip/hip_runtime.h>
#include <cstdint>
#include <cstddef>

#define CC 128

// -------------------- xt = x @ W  (f32 vector FMA, W in LDS) --------------------
__global__ __launch_bounds__(256) void xw_kernel(const float* __restrict__ x,
                                                 const float* __restrict__ W,
                                                 float* __restrict__ xt, int N) {
    __shared__ float Wl[CC * CC];
    const int tid = threadIdx.x;
    for (int i = tid * 4; i < CC * CC; i += 256 * 4) {
        *(float4*)&Wl[i] = *(const float4*)&W[i];
    }
    __syncthreads();
    const int wave = tid >> 6, lane = tid & 63;
    const int c0 = 2 * lane;
    for (int rr = 0; rr < 4; ++rr) {
        const int row = blockIdx.x * 16 + wave * 4 + rr;
        if (row >= N) continue;
        const float4* xrow = (const float4*)(x + (size_t)row * CC);
        float a0 = 0.f, a1 = 0.f;
#pragma unroll 8
        for (int k4 = 0; k4 < 32; ++k4) {
            const float4 xv = xrow[k4];
            const int k = k4 * 4;
            const float2 w0 = *(const float2*)&Wl[(k + 0) * CC + c0];
            const float2 w1 = *(const float2*)&Wl[(k + 1) * CC + c0];
            const float2 w2 = *(const float2*)&Wl[(k + 2) * CC + c0];
            const float2 w3 = *(const float2*)&Wl[(k + 3) * CC + c0];
            a0 += xv.x * w0.x; a1 += xv.x * w0.y;
            a0 += xv.y * w1.x; a1 += xv.y * w1.y;
            a0 += xv.z * w2.x; a1 += xv.z * w2.y;
            a0 += xv.w * w3.x; a1 += xv.w * w3.y;
        }
        *(float2*)&xt[(size_t)row * CC + c0] = make_float2(a0, a1);
    }
}

// -------------------- degrees: D[v] += w[e]; B[e] += 1 --------------------
__global__ __launch_bounds__(256) void deg_kernel(const int* __restrict__ nidx,
                                                  const int* __restrict__ eidx,
                                                  const float* __restrict__ hw,
                                                  float* __restrict__ D,
                                                  float* __restrict__ B, int nnz) {
    for (int i = blockIdx.x * 256 + threadIdx.x; i < nnz; i += gridDim.x * 256) {
        const int v = nidx[i], e = eidx[i];
        atomicAdd(&D[v], hw[e]);
        atomicAdd(&B[e], 1.0f);
    }
}

__global__ __launch_bounds__(256) void inv_kernel(float* __restrict__ D,
                                                  float* __restrict__ B,
                                                  int N, int E) {
    const int i = blockIdx.x * 256 + threadIdx.x;
    if (i < N) { const float d = D[i]; D[i] = d > 0.f ? 1.f / d : 0.f; }
    if (i < E) { const float bb = B[i]; B[i] = bb > 0.f ? 1.f / bb : 0.f; }
}

// -------------------- node -> edge scatter: efeat[e,:] += xt[v,:] --------------------
__global__ __launch_bounds__(256) void scatter_n2e(const int* __restrict__ nidx,
                                                   const int* __restrict__ eidx,
                                                   const float* __restrict__ xt,
                                                   float* __restrict__ efeat, int nnz) {
    const int c = threadIdx.x & 127;
    const int sub = threadIdx.x >> 7;
    for (int i = blockIdx.x * 2 + sub; i < nnz; i += gridDim.x * 2) {
        const int v = nidx[i], e = eidx[i];
        atomicAdd(&efeat[(size_t)e * CC + c], xt[(size_t)v * CC + c]);
    }
}

// -------------------- edge -> node scatter: out[v,:] += Binv[e] * efeat[e,:] --------------------
__global__ __launch_bounds__(256) void scatter_e2n(const int* __restrict__ nidx,
                                                   const int* __restrict__ eidx,
                                                   const float* __restrict__ efeat,
                                                   const float* __restrict__ Binv,
                                                   float* __restrict__ out, int nnz) {
    const int c = threadIdx.x & 127;
    const int sub = threadIdx.x >> 7;
    for (int i = blockIdx.x * 2 + sub; i < nnz; i += gridDim.x * 2) {
        const int v = nidx[i], e = eidx[i];
        const float s = Binv[e];
        atomicAdd(&out[(size_t)v * CC + c], s * efeat[(size_t)e * CC + c]);
    }
}

// -------------------- BN stats: y = acc*Dinv + b; sums/sumsq per channel --------------------
__global__ __launch_bounds__(128) void bn_stats(float* __restrict__ out,
                                                const float* __restrict__ Dinv,
                                                const float* __restrict__ b,
                                                float* __restrict__ sums, int N) {
    const int c = threadIdx.x;
    const float bc = b[c];
    float s = 0.f, sq = 0.f;
    for (int v = blockIdx.x; v < N; v += gridDim.x) {
        const float dinv = Dinv[v];
        float y = out[(size_t)v * CC + c] * dinv + bc;
        out[(size_t)v * CC + c] = y;
        s += y; sq += y * y;
    }
    atomicAdd(&sums[c], s);
    atomicAdd(&sums[CC + c], sq);
}

// -------------------- BN normalize + SiLU --------------------
__global__ __launch_bounds__(128) void bn_silu(float* __restrict__ out,
                                               const float* __restrict__ sums,
                                               const float* __restrict__ gamma,
                                               const float* __restrict__ beta, int N) {
    const int c = threadIdx.x;
    const float invN = 1.0f / (float)N;
    const float mean = sums[c] * invN;
    float var = sums[CC + c] * invN - mean * mean;
    var = fmaxf(var, 0.f);
    const float istd = rsqrtf(var + 1e-5f);
    const float g = gamma[c] * istd;
    const float bb = beta[c] - mean * g;
    for (int v = blockIdx.x; v < N; v += gridDim.x) {
        const float y = out[(size_t)v * CC + c];
        const float z = y * g + bb;
        out[(size_t)v * CC + c] = z / (1.f + __expf(-z));
    }
}

extern "C" void kernel_launch(void* const* d_in, const int* in_sizes, int n_in,
                              void* d_out, int out_size, void* d_ws, size_t ws_size,
                              hipStream_t stream) {
    const float* x     = (const float*)d_in[0];
    const int*   hidx  = (const int*)d_in[1];
    const float* hw    = (const float*)d_in[2];
    const float* W     = (const float*)d_in[3];
    const float* b     = (const float*)d_in[4];
    const float* gamma = (const float*)d_in[5];
    const float* beta  = (const float*)d_in[6];

    const int N   = in_sizes[0] / CC;      // 100000
    const int nnz = in_sizes[1] / 2;       // 1600000
    const int E   = in_sizes[2];           // 50000

    const int* nidx = hidx;
    const int* eidx = hidx + nnz;

    float* out = (float*)d_out;

    float* ws    = (float*)d_ws;
    float* xt    = ws;                                   // N*128
    float* efeat = xt + (size_t)N * CC;                  // E*128
    float* D     = efeat + (size_t)E * CC;               // N
    float* B     = D + N;                                // E
    float* sums  = B + E;                                // 256

    hipMemsetAsync(efeat, 0, (size_t)E * CC * sizeof(float), stream);
    hipMemsetAsync(D, 0, ((size_t)N + E + 256) * sizeof(float), stream);
    hipMemsetAsync(out, 0, (size_t)N * CC * sizeof(float), stream);

    xw_kernel<<<(N + 15) / 16, 256, 0, stream>>>(x, W, xt, N);
    deg_kernel<<<2048, 256, 0, stream>>>(nidx, eidx, hw, D, B, nnz);
    inv_kernel<<<(N + 255) / 256, 256, 0, stream>>>(D, B, N, E);
    scatter_n2e<<<4096, 256, 0, stream>>>(nidx, eidx, xt, efeat, nnz);
    scatter_e2n<<<4096, 256, 0, stream>>>(nidx, eidx, efeat, B, out, nnz);
    bn_stats<<<1024, 128, 0, stream>>>(out, D, b, sums, N);
    bn_silu<<<1024, 128, 0, stream>>>(out, sums, gamma, beta, N);
}

// Round 2
// 774.174 us; speedup vs baseline: 2.2688x; 2.2688x over previous
//
#include <hip/hip_runtime.h>
#include <cstdint>
#include <cstddef>

#define CC 128

// ---------------- histogram: countV[v]++, countE[e]++ ----------------
__global__ __launch_bounds__(256) void hist_kernel(const int* __restrict__ nidx,
                                                   const int* __restrict__ eidx,
                                                   int* __restrict__ countV,
                                                   int* __restrict__ countE, int nnz) {
    for (int i = blockIdx.x * 256 + threadIdx.x; i < nnz; i += gridDim.x * 256) {
        atomicAdd(&countV[nidx[i]], 1);
        atomicAdd(&countE[eidx[i]], 1);
    }
}

// ---------------- single-block exclusive scan (4096 elems/chunk) ----------------
__global__ __launch_bounds__(1024) void scan_kernel(const int* __restrict__ cnt,
                                                    int* __restrict__ rowptr,
                                                    int* __restrict__ cursor, int n) {
    __shared__ int waveSums[16];
    __shared__ int s_carry;
    const int tid = threadIdx.x;
    const int lane = tid & 63;
    const int wv = tid >> 6;
    if (tid == 0) s_carry = 0;
    __syncthreads();
    for (int base = 0; base < n; base += 4096) {
        const int idx = base + tid * 4;
        int4 v = make_int4(0, 0, 0, 0);
        if (idx + 3 < n) {
            v = *(const int4*)&cnt[idx];
        } else if (idx < n) {
            v.x = cnt[idx];
            if (idx + 1 < n) v.y = cnt[idx + 1];
            if (idx + 2 < n) v.z = cnt[idx + 2];
        }
        const int tsum = v.x + v.y + v.z + v.w;
        int incl = tsum;
        for (int d = 1; d < 64; d <<= 1) {
            const int t = __shfl_up(incl, d);
            if (lane >= d) incl += t;
        }
        if (lane == 63) waveSums[wv] = incl;
        __syncthreads();
        if (tid == 0) {
            int run = s_carry;
            for (int w = 0; w < 16; ++w) { const int t = waveSums[w]; waveSums[w] = run; run += t; }
            s_carry = run;
        }
        __syncthreads();
        const int excl = waveSums[wv] + (incl - tsum);
        const int o0 = excl, o1 = o0 + v.x, o2 = o1 + v.y, o3 = o2 + v.z;
        if (idx + 3 < n) {
            *(int4*)&rowptr[idx] = make_int4(o0, o1, o2, o3);
            *(int4*)&cursor[idx] = make_int4(o0, o1, o2, o3);
        } else if (idx < n) {
            rowptr[idx] = o0; cursor[idx] = o0;
            if (idx + 1 < n) { rowptr[idx + 1] = o1; cursor[idx + 1] = o1; }
            if (idx + 2 < n) { rowptr[idx + 2] = o2; cursor[idx + 2] = o2; }
        }
        __syncthreads();
    }
    if (tid == 0) rowptr[n] = s_carry;
}

// ---------------- fill CSR value arrays via cursors ----------------
__global__ __launch_bounds__(256) void fill_kernel(const int* __restrict__ nidx,
                                                   const int* __restrict__ eidx,
                                                   int* __restrict__ curV,
                                                   int* __restrict__ curE,
                                                   int* __restrict__ csrV,
                                                   int* __restrict__ csrE, int nnz) {
    for (int i = blockIdx.x * 256 + threadIdx.x; i < nnz; i += gridDim.x * 256) {
        const int v = nidx[i], e = eidx[i];
        const int pe = atomicAdd(&curE[e], 1);
        csrE[pe] = v;
        const int pv = atomicAdd(&curV[v], 1);
        csrV[pv] = e;
    }
}

// ---------------- hop1: eraw[e,:] = (1/|e|) * sum_{v in e} x[v,:] ----------------
__global__ __launch_bounds__(256) void gather_n2e(const int* __restrict__ rowptrE,
                                                  const int* __restrict__ csrE,
                                                  const float* __restrict__ x,
                                                  float* __restrict__ eraw, int E) {
    const int sub = threadIdx.x >> 5;
    const int lane = threadIdx.x & 31;
    const int e = blockIdx.x * 8 + sub;
    if (e >= E) return;
    const int s = rowptrE[e], t = rowptrE[e + 1];
    float4 acc = make_float4(0.f, 0.f, 0.f, 0.f);
    int j = s;
    for (; j + 1 < t; j += 2) {
        const int v0 = csrE[j], v1 = csrE[j + 1];
        const float4 a = *(const float4*)&x[(size_t)v0 * CC + lane * 4];
        const float4 c = *(const float4*)&x[(size_t)v1 * CC + lane * 4];
        acc.x += a.x + c.x; acc.y += a.y + c.y; acc.z += a.z + c.z; acc.w += a.w + c.w;
    }
    if (j < t) {
        const int v0 = csrE[j];
        const float4 a = *(const float4*)&x[(size_t)v0 * CC + lane * 4];
        acc.x += a.x; acc.y += a.y; acc.z += a.z; acc.w += a.w;
    }
    const float binv = (t > s) ? 1.f / (float)(t - s) : 0.f;
    acc.x *= binv; acc.y *= binv; acc.z *= binv; acc.w *= binv;
    *(float4*)&eraw[(size_t)e * CC + lane * 4] = acc;
}

// ---------------- mm: Out[M,128] = A[M,128] @ W[128,128] ----------------
__global__ __launch_bounds__(256) void mm_kernel(const float* __restrict__ A,
                                                 const float* __restrict__ W,
                                                 float* __restrict__ Out, int M) {
    __shared__ float Wl[CC * CC];   // 64 KB
    __shared__ float Xl[32 * CC];   // 16 KB
    const int tid = threadIdx.x;
    for (int i = tid * 4; i < CC * CC; i += 1024) {
        *(float4*)&Wl[i] = *(const float4*)&W[i];
    }
    const int row0 = blockIdx.x * 32;
    for (int i = tid; i < 1024; i += 256) {
        const int r = i >> 5;
        const int c4 = i & 31;
        const int row = row0 + r;
        float4 v = make_float4(0.f, 0.f, 0.f, 0.f);
        if (row < M) v = *(const float4*)&A[(size_t)row * CC + c4 * 4];
        *(float4*)&Xl[r * CC + c4 * 4] = v;
    }
    __syncthreads();
    const int c4 = (tid & 31) * 4;
    const int rg = tid >> 5;  // 0..7
    float4 acc[4];
#pragma unroll
    for (int r = 0; r < 4; ++r) acc[r] = make_float4(0.f, 0.f, 0.f, 0.f);
    for (int k4 = 0; k4 < 32; ++k4) {
        float4 xv[4];
#pragma unroll
        for (int r = 0; r < 4; ++r) xv[r] = *(const float4*)&Xl[(rg + r * 8) * CC + k4 * 4];
#pragma unroll
        for (int kk = 0; kk < 4; ++kk) {
            const float4 w = *(const float4*)&Wl[(k4 * 4 + kk) * CC + c4];
#pragma unroll
            for (int r = 0; r < 4; ++r) {
                const float xs = (&xv[r].x)[kk];
                acc[r].x += xs * w.x; acc[r].y += xs * w.y;
                acc[r].z += xs * w.z; acc[r].w += xs * w.w;
            }
        }
    }
#pragma unroll
    for (int r = 0; r < 4; ++r) {
        const int row = row0 + rg + r * 8;
        if (row < M) *(float4*)&Out[(size_t)row * CC + c4] = acc[r];
    }
}

// ---------------- hop2: out[v,:] = Dinv_v * sum_{e ni v} efeat[e,:] + b ----------------
__global__ __launch_bounds__(256) void gather_e2n(const int* __restrict__ rowptrV,
                                                  const int* __restrict__ csrV,
                                                  const float* __restrict__ efeat,
                                                  const float* __restrict__ hw,
                                                  const float* __restrict__ b,
                                                  float* __restrict__ out, int N) {
    const int sub = threadIdx.x >> 5;
    const int lane = threadIdx.x & 31;
    const int v = blockIdx.x * 8 + sub;
    if (v >= N) return;
    const int s = rowptrV[v], t = rowptrV[v + 1];
    float4 acc = make_float4(0.f, 0.f, 0.f, 0.f);
    float dsum = 0.f;
    int j = s;
    for (; j + 1 < t; j += 2) {
        const int e0 = csrV[j], e1 = csrV[j + 1];
        dsum += hw[e0] + hw[e1];
        const float4 a = *(const float4*)&efeat[(size_t)e0 * CC + lane * 4];
        const float4 c = *(const float4*)&efeat[(size_t)e1 * CC + lane * 4];
        acc.x += a.x + c.x; acc.y += a.y + c.y; acc.z += a.z + c.z; acc.w += a.w + c.w;
    }
    if (j < t) {
        const int e0 = csrV[j];
        dsum += hw[e0];
        const float4 a = *(const float4*)&efeat[(size_t)e0 * CC + lane * 4];
        acc.x += a.x; acc.y += a.y; acc.z += a.z; acc.w += a.w;
    }
    const float dinv = (dsum > 0.f) ? 1.f / dsum : 0.f;
    const float4 b4 = *(const float4*)&b[lane * 4];
    acc.x = acc.x * dinv + b4.x; acc.y = acc.y * dinv + b4.y;
    acc.z = acc.z * dinv + b4.z; acc.w = acc.w * dinv + b4.w;
    *(float4*)&out[(size_t)v * CC + lane * 4] = acc;
}

// ---------------- BN stats: per-channel sum & sumsq (read-only) ----------------
__global__ __launch_bounds__(512) void bn_stats(const float* __restrict__ out,
                                                float* __restrict__ sums, int N) {
    __shared__ float reds[512];
    __shared__ float redq[512];
    const int c = threadIdx.x & 127;
    const int rg = threadIdx.x >> 7;  // 0..3
    float s = 0.f, sq = 0.f;
    for (int v = blockIdx.x * 4 + rg; v < N; v += gridDim.x * 4) {
        const float y = out[(size_t)v * CC + c];
        s += y; sq += y * y;
    }
    reds[threadIdx.x] = s;
    redq[threadIdx.x] = sq;
    __syncthreads();
    if (rg == 0) {
        const float ts = reds[c] + reds[128 + c] + reds[256 + c] + reds[384 + c];
        const float tq = redq[c] + redq[128 + c] + redq[256 + c] + redq[384 + c];
        atomicAdd(&sums[c], ts);
        atomicAdd(&sums[CC + c], tq);
    }
}

// ---------------- BN normalize + SiLU ----------------
__global__ __launch_bounds__(128) void bn_silu(float* __restrict__ out,
                                               const float* __restrict__ sums,
                                               const float* __restrict__ gamma,
                                               const float* __restrict__ beta, int N) {
    const int c = threadIdx.x;
    const float invN = 1.0f / (float)N;
    const float mean = sums[c] * invN;
    float var = sums[CC + c] * invN - mean * mean;
    var = fmaxf(var, 0.f);
    const float istd = rsqrtf(var + 1e-5f);
    const float g = gamma[c] * istd;
    const float bb = beta[c] - mean * g;
    for (int v = blockIdx.x; v < N; v += gridDim.x) {
        const float y = out[(size_t)v * CC + c];
        const float z = y * g + bb;
        out[(size_t)v * CC + c] = z / (1.f + __expf(-z));
    }
}

extern "C" void kernel_launch(void* const* d_in, const int* in_sizes, int n_in,
                              void* d_out, int out_size, void* d_ws, size_t ws_size,
                              hipStream_t stream) {
    const float* x     = (const float*)d_in[0];
    const int*   hidx  = (const int*)d_in[1];
    const float* hw    = (const float*)d_in[2];
    const float* W     = (const float*)d_in[3];
    const float* b     = (const float*)d_in[4];
    const float* gamma = (const float*)d_in[5];
    const float* beta  = (const float*)d_in[6];

    const int N   = in_sizes[0] / CC;   // 100000
    const int nnz = in_sizes[1] / 2;    // 1600000
    const int E   = in_sizes[2];        // 50000

    const int* nidx = hidx;
    const int* eidx = hidx + nnz;

    float* out = (float*)d_out;

    const int NP = (N + 1 + 3) & ~3;    // padded for int4 access
    const int EP = (E + 1 + 3) & ~3;

    float* ws     = (float*)d_ws;
    float* eraw   = ws;                              // E*CC
    float* efeat  = eraw + (size_t)E * CC;           // E*CC
    float* sums   = efeat + (size_t)E * CC;          // 256
    int*   countV = (int*)(sums + 256);              // NP
    int*   countE = countV + NP;                     // EP
    int*   rowptrV = countE + EP;                    // NP
    int*   rowptrE = rowptrV + NP;                   // EP
    int*   curV   = rowptrE + EP;                    // NP
    int*   curE   = curV + NP;                       // EP
    int*   csrV   = curE + EP;                       // nnz
    int*   csrE   = csrV + nnz;                      // nnz

    // zero: sums (256 floats) + countV + countE (contiguous)
    hipMemsetAsync(sums, 0, (256 + (size_t)NP + EP) * sizeof(int), stream);

    hist_kernel<<<2048, 256, 0, stream>>>(nidx, eidx, countV, countE, nnz);
    scan_kernel<<<1, 1024, 0, stream>>>(countE, rowptrE, curE, E);
    scan_kernel<<<1, 1024, 0, stream>>>(countV, rowptrV, curV, N);
    fill_kernel<<<2048, 256, 0, stream>>>(nidx, eidx, curV, curE, csrV, csrE, nnz);

    gather_n2e<<<(E + 7) / 8, 256, 0, stream>>>(rowptrE, csrE, x, eraw, E);
    mm_kernel<<<(E + 31) / 32, 256, 0, stream>>>(eraw, W, efeat, E);
    gather_e2n<<<(N + 7) / 8, 256, 0, stream>>>(rowptrV, csrV, efeat, hw, b, out, N);

    bn_stats<<<512, 512, 0, stream>>>(out, sums, N);
    bn_silu<<<2048, 128, 0, stream>>>(out, sums, gamma, beta, N);
}